// Round 10
// baseline (444.340 us; speedup 1.0000x reference)
//
#include <hip/hip_runtime.h>
#include <math.h>

#define BB 4
#define NN 1024
#define DD 1024
#define HH 16
#define ROWS (BB*NN)   // 4096

typedef __attribute__((ext_vector_type(8))) short bf16x8;
typedef __attribute__((ext_vector_type(4))) float f32x4;
typedef unsigned short u16;

__device__ __forceinline__ u16 f2bf(float f) {
    union { float f; unsigned u; } v; v.f = f;
    unsigned r = v.u + 0x7fff + ((v.u >> 16) & 1);
    return (u16)(r >> 16);
}
__device__ __forceinline__ float bf2f(u16 u) {
    union { unsigned u; float f; } v; v.u = ((unsigned)u) << 16; return v.f;
}

// async global->LDS, 16B per lane. LDS dest = wave-uniform base (+lane*16 implicit).
__device__ __forceinline__ void async16(const void* g, void* l) {
    __builtin_amdgcn_global_load_lds(
        (__attribute__((address_space(1))) void*)(uintptr_t)g,
        (__attribute__((address_space(3))) void*)(uintptr_t)l,
        16, 0, 0);
}

// ---------------- block reduce ----------------
__device__ __forceinline__ float block_reduce_sum(float v, float* sm) {
    #pragma unroll
    for (int o = 32; o > 0; o >>= 1) v += __shfl_down(v, o);
    int lane = threadIdx.x & 63, wid = threadIdx.x >> 6;
    if (lane == 0) sm[wid] = v;
    __syncthreads();
    if (wid == 0) {
        v = (lane < (int)(blockDim.x >> 6)) ? sm[lane] : 0.f;
        #pragma unroll
        for (int o = 2; o > 0; o >>= 1) v += __shfl_down(v, o);
        if (lane == 0) sm[0] = v;
    }
    __syncthreads();
    float r = sm[0];
    __syncthreads();
    return r;
}

// ---------------- fused: weight transpose+convert (6 weights) AND layernorm1 ----------------
__global__ __launch_bounds__(256) void k_pre(
        const float* __restrict__ Wq_, const float* __restrict__ Wk_,
        const float* __restrict__ Wv_, const float* __restrict__ Wo_,
        const float* __restrict__ Wfc_, const float* __restrict__ Wpj_,
        u16* __restrict__ WqkvT, u16* __restrict__ WoT,
        u16* __restrict__ WfcT, u16* __restrict__ WpjT,
        const float* __restrict__ x, const float* __restrict__ g1,
        const float* __restrict__ be1, u16* __restrict__ lnout) {
    __shared__ float t[32][33];
    int bid = blockIdx.x;
    if (bid < 12352) {
        const float* W; u16* out; int K, N, Kpad, Npad, gx;
        if (bid < 1024)      { W = Wq_;  out = WqkvT;            K = 1024; N = 1024; Kpad = 1024; Npad = 1024; gx = 32; }
        else if (bid < 2048) { W = Wk_;  out = WqkvT + 1048576;  K = 1024; N = 1024; Kpad = 1024; Npad = 1024; gx = 32; bid -= 1024; }
        else if (bid < 3072) { W = Wv_;  out = WqkvT + 2097152;  K = 1024; N = 1024; Kpad = 1024; Npad = 1024; gx = 32; bid -= 2048; }
        else if (bid < 4160) { W = Wo_;  out = WoT;              K = 1040; N = 1023; Kpad = 1088; Npad = 1024; gx = 34; bid -= 3072; }
        else if (bid < 8256) { W = Wfc_; out = WfcT;             K = 1024; N = 4095; Kpad = 1024; Npad = 4096; gx = 32; bid -= 4160; }
        else                 { W = Wpj_; out = WpjT;             K = 4096; N = 1023; Kpad = 4096; Npad = 1024; gx = 128; bid -= 8256; }
        int k0 = (bid % gx) * 32, n0 = (bid / gx) * 32;
        int tx = threadIdx.x & 31, ty = threadIdx.x >> 5;
        #pragma unroll
        for (int i = 0; i < 32; i += 8) {
            int k = k0 + ty + i, n = n0 + tx;
            t[ty + i][tx] = (k < K && n < N) ? W[(size_t)k * N + n] : 0.f;
        }
        __syncthreads();
        #pragma unroll
        for (int i = 0; i < 32; i += 8) {
            int n = n0 + ty + i, k = k0 + tx;
            if (n < Npad && k < Kpad) out[(size_t)n * Kpad + k] = f2bf(t[tx][ty + i]);
        }
    } else {
        float* sm = &t[0][0];
        int row = bid - 12352;
        const float* xr = x + (size_t)row * DD;
        u16* orow = lnout + (size_t)row * DD;
        float s = 0.f, ss = 0.f;
        for (int j = threadIdx.x; j < DD - 1; j += blockDim.x) {
            float v = xr[1 + j]; s += v; ss += v * v;
        }
        s = block_reduce_sum(s, sm);
        ss = block_reduce_sum(ss, sm);
        float mu = s / (float)(DD - 1);
        float var = ss / (float)(DD - 1) - mu * mu;
        float rstd = rsqrtf(var + 1e-5f);
        float s2 = 0.f;
        for (int j = threadIdx.x; j < DD - 1; j += blockDim.x) {
            float v = (xr[1 + j] - mu) * rstd * g1[j] + be1[j];
            orow[1 + j] = f2bf(v); s2 += v * v;
        }
        s2 = block_reduce_sum(s2, sm);
        if (threadIdx.x == 0) orow[0] = f2bf(sqrtf(s2 + 1.f));
    }
}

// ---------------- bf16 MFMA GEMM: single-barrier double-buffered K-loop ----------------
__device__ __forceinline__ void cstore(float* p, float v) { *p = v; }
__device__ __forceinline__ void cstore(u16* p, float v) { *p = f2bf(v); }

template <typename OT>
__global__ __launch_bounds__(256) void k_gemm_mfma(
        const u16* __restrict__ A, const u16* __restrict__ BT,
        const float* __restrict__ bias, int nbias,
        OT* __restrict__ C0, OT* __restrict__ C1,
        int ldc, int ldab, int ksplit, int K) {
    __shared__ __align__(16) u16 As[2][128 * 64];
    __shared__ __align__(16) u16 Bs[2][128 * 64];
    int z = blockIdx.z;
    int kbeg = z ? ksplit : 0;
    int kend = z ? K : ksplit;
    OT* C = z ? C1 : C0;
    const float* bs = z ? nullptr : bias;

    int tid = threadIdx.x;
    int wave = tid >> 6, lane = tid & 63;
    int quad = lane >> 4, m16 = lane & 15;
    int n0 = blockIdx.x * 128, m0 = blockIdx.y * 128;
    int wm = (wave & 1) * 64, wn = (wave >> 1) * 64;

    f32x4 acc[4][4];
    #pragma unroll
    for (int t = 0; t < 4; ++t)
        #pragma unroll
        for (int u = 0; u < 4; ++u) acc[t][u] = (f32x4){0.f, 0.f, 0.f, 0.f};

    int r8 = lane >> 3;
    int cc = (lane & 7) ^ r8;               // XOR chunk swizzle (bank-conflict-free, measured 0)
    int srow = wave * 32 + r8;
    const u16* ag = A  + (size_t)(m0 + srow) * ldab + cc * 8;
    const u16* bg = BT + (size_t)(n0 + srow) * ldab + cc * 8;

    auto stage = [&](int k0, int s) {
        #pragma unroll
        for (int j = 0; j < 4; ++j) {
            async16(ag + (size_t)(j * 8) * ldab + k0, &As[s][(wave * 32 + j * 8) * 64]);
            async16(bg + (size_t)(j * 8) * ldab + k0, &Bs[s][(wave * 32 + j * 8) * 64]);
        }
    };

    int niter = (kend - kbeg) >> 6;
    stage(kbeg, 0);
    for (int it = 0; it < niter; ++it) {
        int cur = it & 1;
        __syncthreads();                    // drains stage(it) + prior iter's LDS reads
        if (it + 1 < niter) stage(kbeg + (it + 1) * 64, cur ^ 1);
        #pragma unroll
        for (int kk = 0; kk < 2; ++kk) {
            bf16x8 af[4], bfr[4];
            #pragma unroll
            for (int t = 0; t < 4; ++t) {
                int slot = (kk * 4 + quad) ^ (m16 & 7);
                af[t] = *(const bf16x8*)&As[cur][(wm + t * 16 + m16) * 64 + slot * 8];
            }
            #pragma unroll
            for (int u = 0; u < 4; ++u) {
                int slot = (kk * 4 + quad) ^ (m16 & 7);
                bfr[u] = *(const bf16x8*)&Bs[cur][(wn + u * 16 + m16) * 64 + slot * 8];
            }
            #pragma unroll
            for (int t = 0; t < 4; ++t)
                #pragma unroll
                for (int u = 0; u < 4; ++u)
                    acc[t][u] = __builtin_amdgcn_mfma_f32_16x16x32_bf16(af[t], bfr[u], acc[t][u], 0, 0, 0);
        }
    }
    #pragma unroll
    for (int u = 0; u < 4; ++u) {
        int col = n0 + wn + u * 16 + m16;
        float bv = (bs != nullptr && col < nbias) ? bs[col] : 0.f;
        #pragma unroll
        for (int t = 0; t < 4; ++t) {
            #pragma unroll
            for (int r = 0; r < 4; ++r) {
                int row = m0 + wm + t * 16 + quad * 4 + r;
                cstore(C + (size_t)row * ldc + col, acc[t][u][r] + bv);
            }
        }
    }
}

// ---------------- fused head builder (Q, K, V via blockIdx.y) ----------------
__global__ __launch_bounds__(256) void k_build_heads(
        const u16* __restrict__ qkv,
        const float* __restrict__ bq, const float* __restrict__ bk,
        const float* __restrict__ bv,
        u16* __restrict__ Qp, u16* __restrict__ Kp, u16* __restrict__ V2) {
    int wid = threadIdx.x >> 6, lane = threadIdx.x & 63;
    int idx = blockIdx.x * 4 + wid;
    int h = idx & 15, bn = idx >> 4;
    int b = bn >> 10, n = bn & 1023;
    int sec = blockIdx.y;
    const float* bias = (sec == 0) ? bq : (sec == 1) ? bk : bv;
    float v = bf2f(qkv[(size_t)bn * 3072 + sec * 1024 + h * 64 + lane]) + bias[h * 64 + lane];
    float ss = v * v;
    #pragma unroll
    for (int o = 32; o > 0; o >>= 1) ss += __shfl_xor(ss, o);
    float tcomp = sqrtf(ss + 1.f);
    size_t bhn = (size_t)(b * 16 + h) * 1024 + n;
    if (sec == 0) {
        u16* drow = Qp + bhn * 96;
        drow[1 + lane] = f2bf(v);
        if (lane == 0) drow[0] = f2bf(-tcomp);
        if (lane < 31) drow[65 + lane] = 0;
    } else if (sec == 1) {
        u16* drow = Kp + bhn * 104;
        drow[1 + lane] = f2bf(v);
        if (lane == 0) drow[0] = f2bf(tcomp);
        if (lane < 39) drow[65 + lane] = 0;
    } else {
        u16* base = V2 + ((size_t)(b * 16 + h) * 16 + (n >> 6)) * 6144 + (n & 63);
        base[(1 + lane) * 72] = f2bf(v);
        if (lane == 0) base[0] = f2bf(tcomp);
        if (lane >= 49) base[(16 + lane) * 72] = 0;   // d = 65..79
    }
}

// ---------------- MFMA flash attention v5 ----------------
// 64 q/block, grid 1024 XCD-swizzled (16 same-bh blocks per XCD, L2 K/V reuse).
// S^T + in-register C->A transpose via __shfl (no Plds): LDS 51.2KB -> 3 blocks/CU.
#define AKS 104
#define AVS 72
#define KTILE_U16 (64 * AKS)   // 6656
#define VTILE_U16 6144
#define EXPC 0.36067376f       // 0.25 * log2(e)
__global__ __launch_bounds__(256) void k_attn_mfma(
        const u16* __restrict__ Qp, const u16* __restrict__ Kp,
        const u16* __restrict__ V2, u16* __restrict__ cat) {
    __shared__ __align__(16) u16 Klds[2][KTILE_U16];
    __shared__ __align__(16) u16 Vlds[2][VTILE_U16];
    int tid = threadIdx.x;
    int wave = tid >> 6, lane = tid & 63;
    int quad = lane >> 4, m = lane & 15;
    // XCD swizzle: bid ≡ c (mod 8) share an XCD; all 16 qt-blocks of one bh on one XCD.
    int bid = blockIdx.x;
    int bh = ((bid & 7) << 3) | (bid >> 7);
    int qt = (bid >> 3) & 15;

    const u16* kg = Kp + (size_t)bh * 16 * KTILE_U16;
    const u16* vg = V2 + (size_t)bh * 16 * VTILE_U16;

    // Q fragments: this wave's 16 queries
    const u16* qptr = Qp + ((size_t)bh * 1024 + qt * 64 + wave * 16 + m) * 96;
    bf16x8 aq0 = *(const bf16x8*)(qptr + quad * 8);
    bf16x8 aq1 = *(const bf16x8*)(qptr + 32 + quad * 8);
    bf16x8 aq2 = *(const bf16x8*)(qptr + 64 + quad * 8);

    f32x4 O[5];
    #pragma unroll
    for (int i = 0; i < 5; ++i) O[i] = (f32x4){0.f, 0.f, 0.f, 0.f};

    auto stage = [&](int kt, int s) {
        const u16* kt_p = kg + kt * KTILE_U16 + lane * 8;
        const u16* vt_p = vg + kt * VTILE_U16 + lane * 8;
        for (int i = wave; i < 25; i += 4) {
            if (i < 13) async16(kt_p + i * 512, &Klds[s][i * 512]);
            else        async16(vt_p + (i - 13) * 512, &Vlds[s][(i - 13) * 512]);
        }
    };

    int srcA = (quad & 1) * 32 + m;   // source lane for ap dwords 0,1
    int srcB = srcA + 16;             // source lane for ap dwords 2,3
    bool ntHi = (quad >> 1) != 0;     // quads 2,3 use nt=2kc+1

    stage(0, 0);
    for (int kt = 0; kt < 16; ++kt) {
        int cur = kt & 1;
        __syncthreads();
        if (kt < 15) stage(kt + 1, cur ^ 1);
        // S^T scores: lane(quad,m) -> keys nt*16+quad*4+0..3, query m; packed bf16 pairs
        uint2 pkk[4];
        #pragma unroll
        for (int nt = 0; nt < 4; ++nt) {
            f32x4 acc = (f32x4){0.f, 0.f, 0.f, 0.f};
            const u16* kr = &Klds[cur][(nt * 16 + m) * AKS + quad * 8];
            acc = __builtin_amdgcn_mfma_f32_16x16x32_bf16(*(const bf16x8*)(kr),      aq0, acc, 0, 0, 0);
            acc = __builtin_amdgcn_mfma_f32_16x16x32_bf16(*(const bf16x8*)(kr + 32), aq1, acc, 0, 0, 0);
            acc = __builtin_amdgcn_mfma_f32_16x16x32_bf16(*(const bf16x8*)(kr + 64), aq2, acc, 0, 0, 0);
            union { float f; unsigned u; } a0, a1, a2, a3;
            a0.f = __builtin_amdgcn_exp2f(fmaf(acc[0], EXPC, EXPC));
            a1.f = __builtin_amdgcn_exp2f(fmaf(acc[1], EXPC, EXPC));
            a2.f = __builtin_amdgcn_exp2f(fmaf(acc[2], EXPC, EXPC));
            a3.f = __builtin_amdgcn_exp2f(fmaf(acc[3], EXPC, EXPC));
            pkk[nt].x = ((a0.u + 0x8000u) >> 16) | (((a1.u + 0x8000u) >> 16) << 16);
            pkk[nt].y = ((a2.u + 0x8000u) >> 16) | (((a3.u + 0x8000u) >> 16) << 16);
        }
        // PV with in-register transpose: ap(kc) = P[q=m][keys kc*32+quad*8..+7]
        #pragma unroll
        for (int kc = 0; kc < 2; ++kc) {
            uint2 lo = pkk[2 * kc], hi = pkk[2 * kc + 1];
            unsigned d0a = __shfl((int)lo.x, srcA), d0b = __shfl((int)hi.x, srcA);
            unsigned d1a = __shfl((int)lo.y, srcA), d1b = __shfl((int)hi.y, srcA);
            unsigned d2a = __shfl((int)lo.x, srcB), d2b = __shfl((int)hi.x, srcB);
            unsigned d3a = __shfl((int)lo.y, srcB), d3b = __shfl((int)hi.y, srcB);
            union { uint4 u; bf16x8 v; } apu;
            apu.u.x = ntHi ? d0b : d0a;
            apu.u.y = ntHi ? d1b : d1a;
            apu.u.z = ntHi ? d2b : d2a;
            apu.u.w = ntHi ? d3b : d3a;
            #pragma unroll
            for (int vt = 0; vt < 5; ++vt) {
                bf16x8 bv = *(const bf16x8*)&Vlds[cur][(vt * 16 + m) * AVS + kc * 32 + quad * 8];
                O[vt] = __builtin_amdgcn_mfma_f32_16x16x32_bf16(apu.v, bv, O[vt], 0, 0, 0);
            }
        }
    }
    // epilogue: Lorentz normalize rows, write cat (stride 1088)
    int b = bh >> 4, h = bh & 15;
    #pragma unroll
    for (int r = 0; r < 4; ++r) {
        float part = 0.f;
        #pragma unroll
        for (int vt = 0; vt < 5; ++vt) {
            int c = vt * 16 + m;
            float o = O[vt][r];
            part += (c == 0) ? o * o : -o * o;
        }
        part += __shfl_xor(part, 1);
        part += __shfl_xor(part, 2);
        part += __shfl_xor(part, 4);
        part += __shfl_xor(part, 8);
        float rden = rsqrtf(fmaxf(part, 1e-8f));
        int n = qt * 64 + wave * 16 + quad * 4 + r;
        u16* crow = cat + (size_t)(b * 1024 + n) * 1088 + h * 65;
        #pragma unroll
        for (int vt = 0; vt < 5; ++vt) {
            int c = vt * 16 + m;
            if (c < 65) crow[c] = f2bf(O[vt][r] * rden);
        }
    }
    // zero pad cols 1040..1087 for this block's 64 rows (one h-slot per (b,qt))
    if (h == 15) {
        for (int i = tid; i < 64 * 48; i += 256) {
            int rr = i / 48, c = i - rr * 48;
            int n = qt * 64 + rr;
            cat[(size_t)(b * 1024 + n) * 1088 + 1040 + c] = 0;
        }
    }
}

// ---------------- fused lift(y0+y1) + lresnet + layernorm2 (row-local) ----------------
__global__ __launch_bounds__(256) void k_lresnet_ln(
        const float* __restrict__ x, const float* __restrict__ y0,
        const float* __restrict__ y1, const float* __restrict__ wscale,
        const float* __restrict__ g2, const float* __restrict__ be2,
        float* __restrict__ x1, u16* __restrict__ lnout) {
    __shared__ float sm[8];
    int row = blockIdx.x;
    const float* xr = x + (size_t)row * DD;
    const float* ya = y0 + (size_t)row * 1024;
    const float* yb = y1 + (size_t)row * 1024;
    float w = *wscale;
    float zreg[4];
    float sy = 0.f, sz = 0.f, szs = 0.f;
    int cnt = 0;
    for (int j = threadIdx.x; j < DD - 1; j += blockDim.x) {
        float yv = ya[j] + yb[j];
        float zv = xr[1 + j] + w * yv;
        sy += yv * yv; sz += zv * zv; szs += zv;
        zreg[cnt++] = zv;
    }
    sy = block_reduce_sum(sy, sm);
    sz = block_reduce_sum(sz, sm);
    szs = block_reduce_sum(szs, sm);
    float y0t = sqrtf(sy + 1.f);
    float z0 = xr[0] + w * y0t;
    float q = z0 * z0 - sz;
    float rden = rsqrtf(fmaxf(q, 1e-8f));
    float mu = rden * szs / (float)(DD - 1);
    float ex2 = rden * rden * sz / (float)(DD - 1);
    float var = ex2 - mu * mu;
    float rstd = rsqrtf(var + 1e-5f);
    float s2 = 0.f;
    cnt = 0;
    float* x1r = x1 + (size_t)row * DD;
    u16* lr = lnout + (size_t)row * DD;
    for (int j = threadIdx.x; j < DD - 1; j += blockDim.x) {
        float xv = zreg[cnt++] * rden;
        x1r[1 + j] = xv;
        float v = (xv - mu) * rstd * g2[j] + be2[j];
        lr[1 + j] = f2bf(v); s2 += v * v;
    }
    s2 = block_reduce_sum(s2, sm);
    if (threadIdx.x == 0) {
        x1r[0] = z0 * rden;
        lr[0] = f2bf(sqrtf(s2 + 1.f));
    }
}

// ---------------- final lresnet (fp32 out) ----------------
__global__ __launch_bounds__(256) void k_lresnet(
        const float* __restrict__ x, const float* __restrict__ y0,
        const float* __restrict__ y1, const float* __restrict__ wscale,
        float* __restrict__ out) {
    __shared__ float sm[8];
    int row = blockIdx.x;
    const float* xr = x + (size_t)row * DD;
    const float* ya = y0 + (size_t)row * 1024;
    const float* yb = y1 + (size_t)row * 1024;
    float w = *wscale;
    float zreg[4];
    float sy = 0.f, sz = 0.f;
    int cnt = 0;
    for (int j = threadIdx.x; j < DD - 1; j += blockDim.x) {
        float yv = ya[j] + yb[j];
        float zv = xr[1 + j] + w * yv;
        sy += yv * yv; sz += zv * zv;
        zreg[cnt++] = zv;
    }
    sy = block_reduce_sum(sy, sm);
    sz = block_reduce_sum(sz, sm);
    float y0t = sqrtf(sy + 1.f);
    float z0 = xr[0] + w * y0t;
    float q = z0 * z0 - sz;
    float rden = rsqrtf(fmaxf(q, 1e-8f));
    cnt = 0;
    for (int j = threadIdx.x; j < DD - 1; j += blockDim.x)
        out[(size_t)row * DD + 1 + j] = zreg[cnt++] * rden;
    if (threadIdx.x == 0) out[(size_t)row * DD] = z0 * rden;
}

// ---------------- gelu (exact) + lift: bf16 in -> bf16 lifted out ----------------
__global__ __launch_bounds__(256) void k_gelu_lift(
        const u16* __restrict__ hfc, u16* __restrict__ hg) {
    __shared__ float sm[8];
    int row = blockIdx.x;
    const u16* hr = hfc + (size_t)row * 4096;
    u16* gr = hg + (size_t)row * 4096;
    float s2 = 0.f;
    for (int j = threadIdx.x; j < 4095; j += blockDim.x) {
        float v = bf2f(hr[j]);
        float gl = 0.5f * v * (1.f + erff(v * 0.70710678f));
        gr[1 + j] = f2bf(gl); s2 += gl * gl;
    }
    s2 = block_reduce_sum(s2, sm);
    if (threadIdx.x == 0) gr[0] = f2bf(sqrtf(s2 + 1.f));
}

// ---------------- launch ----------------
extern "C" void kernel_launch(void* const* d_in, const int* in_sizes, int n_in,
                              void* d_out, int out_size, void* d_ws, size_t ws_size,
                              hipStream_t stream) {
    const float* x   = (const float*)d_in[0];
    const float* g1  = (const float*)d_in[1];
    const float* b1  = (const float*)d_in[2];
    const float* Wq  = (const float*)d_in[3];
    const float* bq  = (const float*)d_in[4];
    const float* Wk  = (const float*)d_in[5];
    const float* bk  = (const float*)d_in[6];
    const float* Wv  = (const float*)d_in[7];
    const float* bv  = (const float*)d_in[8];
    const float* Wo  = (const float*)d_in[9];
    const float* bo  = (const float*)d_in[10];
    const float* g2  = (const float*)d_in[11];
    const float* b2  = (const float*)d_in[12];
    const float* Wfc = (const float*)d_in[13];
    const float* bfc = (const float*)d_in[14];
    const float* Wpj = (const float*)d_in[15];
    const float* bpj = (const float*)d_in[16];
    const float* w1  = (const float*)d_in[17];
    const float* w2  = (const float*)d_in[18];
    float* out = (float*)d_out;

    char* W = (char*)d_ws;
    // byte offsets; peak 117,571,584 B
    u16* lx_bf  = (u16*)(W + 0);            // 8 MB (ln1, later ln2)
    u16* WqkvT  = (u16*)(W + 8388608);      // [3072][1024]
    u16* WoT    = (u16*)(W + 14680064);     // [1024][1088]
    u16* WfcT   = (u16*)(W + 16908288);     // [4096][1024]
    u16* WpjT   = (u16*)(W + 25296896);     // [1024][4096]
    u16* qkv_bf = (u16*)(W + 33685504);     // 4096x3072 (dead after builders)
    u16* Qp     = (u16*)(W + 58851328);     // 64x1024x96
    u16* Kp     = (u16*)(W + 71434240);     // 64x1024x104
    u16* V2     = (u16*)(W + 85065728);     // 64x16x6144
    u16* cat_bf = (u16*)(W + 97648640);     // 4096x1088
    float* ax0  = (float*)(W + 33685504);   // overlay qkv (dead)
    float* ax1  = (float*)(W + 50462720);   // overlay qkv/Qp-head (dead)
    float* x1   = (float*)(W + 67239936);   // overlay Qp-tail/Kp (dead)
    u16* hfc_bf = (u16*)(W + 84017152);     // 32MB, overlay Kp-tail/V2/cat (dead)
    u16* hg_bf  = (u16*)(W + 33685504);     // 32MB, overlay ax0/ax1 (dead)
    float* h2a  = (float*)(W + 84017152);   // overlay hfc (dead after gelu)
    float* h2b  = (float*)(W + 100794368);

    dim3 blk(256);

    // 1) weight conversion + layernorm1 (fused)
    k_pre<<<16448, blk, 0, stream>>>(Wq, Wk, Wv, Wo, Wfc, Wpj,
                                     WqkvT, WoT, WfcT, WpjT,
                                     x, g1, b1, lx_bf);

    // 2) fused QKV GEMM + head layouts
    k_gemm_mfma<u16><<<dim3(24, 32, 1), blk, 0, stream>>>(
        lx_bf, WqkvT, nullptr, 0, qkv_bf, qkv_bf, 3072, 1024, 1024, 1024);
    k_build_heads<<<dim3(ROWS * HH / 4, 3), blk, 0, stream>>>(
        qkv_bf, bq, bk, bv, Qp, Kp, V2);

    // 3) MFMA flash attention v5 (1024 blocks, XCD-swizzled, 3 blocks/CU)
    k_attn_mfma<<<1024, blk, 0, stream>>>(Qp, Kp, V2, cat_bf);

    // 4) ax = cat @ Wo + bo, split-K (576+512)
    k_gemm_mfma<float><<<dim3(8, 32, 2), blk, 0, stream>>>(
        cat_bf, WoT, bo, 1023, ax0, ax1, 1024, 1088, 576, 1088);

    // 5) x1 = lresnet(x, lift(ax0+ax1), w1); ln2 -> lx_bf (fused)
    k_lresnet_ln<<<ROWS, blk, 0, stream>>>(x, ax0, ax1, w1, g2, b2, x1, lx_bf);

    // 6) hfc = ln2 @ Wfc + bfc (bf16 out)
    k_gemm_mfma<u16><<<dim3(32, 32, 1), blk, 0, stream>>>(
        lx_bf, WfcT, bfc, 4095, hfc_bf, hfc_bf, 4096, 1024, 1024, 1024);

    // 7) hg = lift(gelu(hfc)) bf16
    k_gelu_lift<<<ROWS, blk, 0, stream>>>(hfc_bf, hg_bf);

    // 8) h2 = hg @ Wpj + bpj, split-K (2048+2048)
    k_gemm_mfma<float><<<dim3(8, 32, 2), blk, 0, stream>>>(
        hg_bf, WpjT, bpj, 1023, h2a, h2b, 1024, 4096, 2048, 4096);

    // 9) out = lresnet(x1, lift(h2a+h2b), w2)
    k_lresnet<<<ROWS, blk, 0, stream>>>(x1, h2a, h2b, w2, out);
}